// Round 1
// baseline (409.909 us; speedup 1.0000x reference)
//
#include <hip/hip_runtime.h>
#include <stdint.h>

typedef unsigned short u16;
typedef __attribute__((ext_vector_type(8))) short short8;
typedef __attribute__((ext_vector_type(4))) float f32x4;

#define BATCH 16384L

__device__ __forceinline__ u16 f2bf(float f) {
    union { float f; uint32_t u; } cv; cv.f = f;
    uint32_t u = cv.u;
    u = (u + 0x7fffu + ((u >> 16) & 1u)) >> 16;
    return (u16)u;
}
__device__ __forceinline__ float bf2f(u16 h) {
    union { uint32_t u; float f; } cv; cv.u = ((uint32_t)h) << 16;
    return cv.f;
}

// ---------------------------------------------------------------------------
// Kernel 1: per-batch gram pairs (hi/lo split bf16 MFMA ~ fp32 accuracy)
//           + emit bf16 copy of x (each wave loads its b's 32x64 exactly once)
// ---------------------------------------------------------------------------
__global__ __launch_bounds__(256) void k_gram(const float* __restrict__ x,
                                              const float* __restrict__ Wc,
                                              u16* __restrict__ xb,
                                              float* __restrict__ spair) {
    const int wave = threadIdx.x >> 6;
    const int lane = threadIdx.x & 63;
    const long b = (long)blockIdx.x * 4 + wave;
    const int r16 = lane & 15, quad = lane >> 4;
    const float* xg = x + b * 2048;

    short8 hi[2][2], lo[2][2];
    for (int mt = 0; mt < 2; mt++) {
        for (int k0 = 0; k0 < 2; k0++) {
            const int row = mt * 16 + r16;
            const int kof = k0 * 32 + quad * 8;
            const float* p = xg + row * 64 + kof;
            float4 p0 = *(const float4*)p;
            float4 p1 = *(const float4*)(p + 4);
            float v[8] = {p0.x, p0.y, p0.z, p0.w, p1.x, p1.y, p1.z, p1.w};
            short8 h, l;
            for (int j = 0; j < 8; j++) {
                u16 hb = f2bf(v[j]);
                h[j] = (short)hb;
                l[j] = (short)f2bf(v[j] - bf2f(hb));
            }
            hi[mt][k0] = h; lo[mt][k0] = l;
            *(short8*)(xb + b * 2048 + row * 64 + kof) = h;  // bf16 x for GEMM1
        }
    }
    f32x4 zero = {0.f, 0.f, 0.f, 0.f};
    f32x4 acc[2][2];
    for (int mt = 0; mt < 2; mt++) for (int nt = 0; nt < 2; nt++) acc[mt][nt] = zero;
    for (int k0 = 0; k0 < 2; k0++)
        for (int mt = 0; mt < 2; mt++)
            for (int nt = 0; nt < 2; nt++) {
                acc[mt][nt] = __builtin_amdgcn_mfma_f32_16x16x32_bf16(hi[mt][k0], hi[nt][k0], acc[mt][nt], 0, 0, 0);
                acc[mt][nt] = __builtin_amdgcn_mfma_f32_16x16x32_bf16(hi[mt][k0], lo[nt][k0], acc[mt][nt], 0, 0, 0);
                acc[mt][nt] = __builtin_amdgcn_mfma_f32_16x16x32_bf16(lo[mt][k0], hi[nt][k0], acc[mt][nt], 0, 0, 0);
            }
    // pairs: upper triangle i<j, p = 31*i - i*(i-1)/2 + (j-i-1); weight Wc[64+p]
    float pacc = 0.f;
    for (int mt = 0; mt < 2; mt++)
        for (int nt = 0; nt < 2; nt++)
            for (int r = 0; r < 4; r++) {
                int row = mt * 16 + quad * 4 + r;
                int col = nt * 16 + r16;
                if (col > row) {
                    int p = 31 * row - (row * (row - 1)) / 2 + (col - row - 1);
                    pacc += acc[mt][nt][r] * Wc[64 + p];
                }
            }
    for (int off = 1; off < 64; off <<= 1) pacc += __shfl_xor(pacc, off);
    if (lane == 0) spair[b] = pacc;
}

// ---------------------------------------------------------------------------
// Kernel 2: fp32 -> bf16 transpose (W (KxN) -> WT (NxK)) for GEMM B^T input
// ---------------------------------------------------------------------------
__global__ __launch_bounds__(256) void k_transpose_bf16(const float* __restrict__ W,
                                                        u16* __restrict__ WT,
                                                        int K, int N) {
    __shared__ float tile[32][33];
    const int nb = blockIdx.x * 32, kb = blockIdx.y * 32;
    const int tx = threadIdx.x & 31, ty = threadIdx.x >> 5;  // ty 0..7
    for (int r = ty; r < 32; r += 8) tile[r][tx] = W[(long)(kb + r) * N + nb + tx];
    __syncthreads();
    for (int r = ty; r < 32; r += 8) WT[(long)(nb + r) * K + kb + tx] = f2bf(tile[tx][r]);
}

// ---------------------------------------------------------------------------
// Kernel 3: bf16 GEMM (m97 structure): C = relu(A @ Bt^T + bias) -> bf16
//           + per-column sum/sumsq atomics for batchnorm
// A: MxK row-major bf16, Bt: NxK row-major bf16. 128x128 tile, BK=32.
// ---------------------------------------------------------------------------
__global__ __launch_bounds__(256) void gemm_bn(const u16* __restrict__ A,
                                               const u16* __restrict__ Bt,
                                               const float* __restrict__ bias,
                                               u16* __restrict__ C,
                                               float* __restrict__ sums,
                                               float* __restrict__ ssq,
                                               int M, int N, int K) {
    __shared__ u16 lA[128 * 32];
    __shared__ u16 lB[128 * 32];
    const int tid = threadIdx.x;
    const int lane = tid & 63, wave = tid >> 6;
    const int wm = wave >> 1, wn = wave & 1;
    const int quad = lane >> 4, r16 = lane & 15;
    const long m0 = (long)blockIdx.y * 128;
    const long n0 = (long)blockIdx.x * 128;

    f32x4 zero = {0.f, 0.f, 0.f, 0.f};
    f32x4 acc[4][4];
    for (int mt = 0; mt < 4; mt++) for (int nt = 0; nt < 4; nt++) acc[mt][nt] = zero;

    for (long k0 = 0; k0 < K; k0 += 32) {
        __syncthreads();  // all waves done reading previous tile
        for (int i = 0; i < 2; i++) {
            const int c = tid + 256 * i;           // 0..511
            const int row = c >> 2, kc = c & 3;    // 16B chunk per lane
            const u16* ga = A + (m0 + row) * K + k0 + kc * 8;
            const u16* gb = Bt + (n0 + row) * K + k0 + kc * 8;
            __builtin_amdgcn_global_load_lds((const __attribute__((address_space(1))) void*)ga,
                                             (__attribute__((address_space(3))) void*)(&lA[c * 8]), 16, 0, 0);
            __builtin_amdgcn_global_load_lds((const __attribute__((address_space(1))) void*)gb,
                                             (__attribute__((address_space(3))) void*)(&lB[c * 8]), 16, 0, 0);
        }
        __syncthreads();  // vmcnt drained by barrier semantics
        short8 af[4], bfr[4];
        for (int mt = 0; mt < 4; mt++)
            af[mt] = *(const short8*)&lA[(wm * 64 + mt * 16 + r16) * 32 + quad * 8];
        for (int nt = 0; nt < 4; nt++)
            bfr[nt] = *(const short8*)&lB[(wn * 64 + nt * 16 + r16) * 32 + quad * 8];
        for (int mt = 0; mt < 4; mt++)
            for (int nt = 0; nt < 4; nt++)
                acc[mt][nt] = __builtin_amdgcn_mfma_f32_16x16x32_bf16(af[mt], bfr[nt], acc[mt][nt], 0, 0, 0);
    }

    // epilogue: bias + relu + bf16 store + BN stats (quad-shuffle -> atomic)
    for (int nt = 0; nt < 4; nt++) {
        const int col = (int)n0 + wn * 64 + nt * 16 + r16;
        const float bcol = bias[col];
        float s = 0.f, sq = 0.f;
        for (int mt = 0; mt < 4; mt++)
            for (int r = 0; r < 4; r++) {
                const long row = m0 + wm * 64 + mt * 16 + quad * 4 + r;
                float v = acc[mt][nt][r] + bcol;
                v = fmaxf(v, 0.f);
                C[row * N + col] = f2bf(v);
                s += v; sq += v * v;
            }
        s += __shfl_xor(s, 16);  s += __shfl_xor(s, 32);
        sq += __shfl_xor(sq, 16); sq += __shfl_xor(sq, 32);
        if (quad == 0) { atomicAdd(&sums[col], s); atomicAdd(&ssq[col], sq); }
    }
}

// ---------------------------------------------------------------------------
// Kernel 4: finalize BN affine: a = g*rsqrt(var+eps), c = beta - a*mean
// ---------------------------------------------------------------------------
__global__ void k_stat(const float* __restrict__ sums, const float* __restrict__ ssq,
                       const float* __restrict__ g, const float* __restrict__ beta,
                       float* __restrict__ a, float* __restrict__ c, int n, float invB) {
    const int k = blockIdx.x * 256 + threadIdx.x;
    if (k < n) {
        const float m = sums[k] * invB;
        const float var = ssq[k] * invB - m * m;
        const float s = g[k] * rsqrtf(var + 1e-5f);
        a[k] = s; c[k] = beta[k] - s * m;
    }
}

// ---------------------------------------------------------------------------
// Kernel 5: in-place normalize h (bf16), per-column affine. 8 elems/thread.
// ---------------------------------------------------------------------------
__global__ __launch_bounds__(256) void k_norm(u16* __restrict__ h,
                                              const float* __restrict__ a,
                                              const float* __restrict__ c) {
    const long i = ((long)blockIdx.x * 256 + threadIdx.x) * 8;
    const int colb = (int)(i & 1023);
    short8 v = *(short8*)&h[i];
    short8 o;
    for (int j = 0; j < 8; j++) {
        const float f = bf2f((u16)v[j]);
        o[j] = (short)f2bf(a[colb + j] * f + c[colb + j]);
    }
    *(short8*)&h[i] = o;
}

// ---------------------------------------------------------------------------
// Kernel 6: fold GEMM3 + concat + head: v[k] = W3[k,:].Wc[:64]; c0 = b3.Wc+bc
// ---------------------------------------------------------------------------
__global__ void k_v(const float* __restrict__ W3, const float* __restrict__ b3,
                    const float* __restrict__ Wc, const float* __restrict__ bc,
                    float* __restrict__ v, float* __restrict__ c0) {
    const int k = blockIdx.x * 256 + threadIdx.x;
    if (k < 512) {
        float s = 0.f;
        for (int j = 0; j < 64; j++) s += W3[k * 64 + j] * Wc[j];
        v[k] = s;
    }
    if (k == 0) {
        float s = 0.f;
        for (int j = 0; j < 64; j++) s += b3[j] * Wc[j];
        *c0 = s + bc[0];
    }
}

// ---------------------------------------------------------------------------
// Kernel 7: out[b] = sum_k (a2[k]*h2[b,k]+c2[k])*v[k] + spair[b] + c0
// One wave per row.
// ---------------------------------------------------------------------------
__global__ __launch_bounds__(256) void k_final(const u16* __restrict__ h2,
                                               const float* __restrict__ a2,
                                               const float* __restrict__ c2,
                                               const float* __restrict__ v,
                                               const float* __restrict__ c0,
                                               const float* __restrict__ spair,
                                               float* __restrict__ out) {
    const int wave = threadIdx.x >> 6, lane = threadIdx.x & 63;
    const long b = (long)blockIdx.x * 4 + wave;
    const int k0 = lane * 8;
    short8 hv = *(const short8*)&h2[b * 512 + k0];
    float acc = 0.f;
    for (int j = 0; j < 8; j++) {
        const int k = k0 + j;
        const float f = bf2f((u16)hv[j]);
        acc += (a2[k] * f + c2[k]) * v[k];
    }
    for (int off = 1; off < 64; off <<= 1) acc += __shfl_xor(acc, off);
    if (lane == 0) out[b] = acc + spair[b] + c0[0];
}

// ---------------------------------------------------------------------------
extern "C" void kernel_launch(void* const* d_in, const int* in_sizes, int n_in,
                              void* d_out, int out_size, void* d_ws, size_t ws_size,
                              hipStream_t stream) {
    const float* x     = (const float*)d_in[0];
    const float* W1    = (const float*)d_in[1];
    const float* b1    = (const float*)d_in[2];
    const float* g1    = (const float*)d_in[3];
    const float* beta1 = (const float*)d_in[4];
    const float* W2    = (const float*)d_in[5];
    const float* b2    = (const float*)d_in[6];
    const float* g2    = (const float*)d_in[7];
    const float* beta2 = (const float*)d_in[8];
    const float* W3    = (const float*)d_in[9];
    const float* b3    = (const float*)d_in[10];
    const float* Wc    = (const float*)d_in[11];
    const float* bc    = (const float*)d_in[12];
    float* out = (float*)d_out;

    char* ws = (char*)d_ws;
    size_t o = 0;
    u16* xb  = (u16*)(ws + o); o += BATCH * 2048 * 2;       // 67.1 MB
    u16* w1t = (u16*)(ws + o); o += 2048L * 1024 * 2;       //  4.2 MB
    u16* w2t = (u16*)(ws + o); o += 1024L * 512 * 2;        //  1.0 MB
    u16* h1b = (u16*)(ws + o); o += BATCH * 1024 * 2;       // 33.6 MB
    u16* h2b = (u16*)(ws + o); o += BATCH * 512 * 2;        // 16.8 MB
    float* spair = (float*)(ws + o); o += BATCH * 4;
    float* stats = (float*)(ws + o); o += 3072 * 4;         // sums1|ssq1|sums2|ssq2
    float* sums1 = stats, *ssq1 = stats + 1024, *sums2 = stats + 2048, *ssq2 = stats + 2560;
    float* a1 = (float*)(ws + o); o += 1024 * 4;
    float* c1 = (float*)(ws + o); o += 1024 * 4;
    float* a2 = (float*)(ws + o); o += 512 * 4;
    float* c2 = (float*)(ws + o); o += 512 * 4;
    float* vv = (float*)(ws + o); o += 512 * 4;
    float* c0 = (float*)(ws + o); o += 4;

    hipMemsetAsync(stats, 0, 3072 * 4, stream);
    k_gram<<<4096, 256, 0, stream>>>(x, Wc, xb, spair);
    k_transpose_bf16<<<dim3(1024 / 32, 2048 / 32), 256, 0, stream>>>(W1, w1t, 2048, 1024);
    k_transpose_bf16<<<dim3(512 / 32, 1024 / 32), 256, 0, stream>>>(W2, w2t, 1024, 512);
    gemm_bn<<<dim3(8, 128), 256, 0, stream>>>(xb, w1t, b1, h1b, sums1, ssq1, 16384, 1024, 2048);
    k_stat<<<4, 256, 0, stream>>>(sums1, ssq1, g1, beta1, a1, c1, 1024, 1.f / 16384.f);
    k_norm<<<8192, 256, 0, stream>>>(h1b, a1, c1);
    gemm_bn<<<dim3(4, 128), 256, 0, stream>>>(h1b, w2t, b2, h2b, sums2, ssq2, 16384, 512, 1024);
    k_stat<<<2, 256, 0, stream>>>(sums2, ssq2, g2, beta2, a2, c2, 512, 1.f / 16384.f);
    k_v<<<2, 256, 0, stream>>>(W3, b3, Wc, bc, vv, c0);
    k_final<<<4096, 256, 0, stream>>>(h2b, a2, c2, vv, c0, spair, out);
}

// Round 2
// 365.856 us; speedup vs baseline: 1.1204x; 1.1204x over previous
//
#include <hip/hip_runtime.h>
#include <stdint.h>

typedef unsigned short u16;
typedef __attribute__((ext_vector_type(8))) short short8;
typedef __attribute__((ext_vector_type(4))) float f32x4;

#define BATCH 16384L

__device__ __forceinline__ u16 f2bf(float f) {
    union { float f; uint32_t u; } cv; cv.f = f;
    uint32_t u = cv.u;
    u = (u + 0x7fffu + ((u >> 16) & 1u)) >> 16;
    return (u16)u;
}
__device__ __forceinline__ float bf2f(u16 h) {
    union { uint32_t u; float f; } cv; cv.u = ((uint32_t)h) << 16;
    return cv.f;
}

// ---------------------------------------------------------------------------
// Kernel 1: per-batch gram pairs (hi/lo split bf16 MFMA ~ fp32 accuracy)
//           + emit bf16 copy of x (reads x exactly once)
// ---------------------------------------------------------------------------
__global__ __launch_bounds__(256) void k_gram(const float* __restrict__ x,
                                              const float* __restrict__ Wc,
                                              u16* __restrict__ xb,
                                              float* __restrict__ spair) {
    const int wave = threadIdx.x >> 6;
    const int lane = threadIdx.x & 63;
    const long b = (long)blockIdx.x * 4 + wave;
    const int r16 = lane & 15, quad = lane >> 4;
    const float* xg = x + b * 2048;

    short8 hi[2][2], lo[2][2];
    for (int mt = 0; mt < 2; mt++) {
        for (int k0 = 0; k0 < 2; k0++) {
            const int row = mt * 16 + r16;
            const int kof = k0 * 32 + quad * 8;
            const float* p = xg + row * 64 + kof;
            float4 p0 = *(const float4*)p;
            float4 p1 = *(const float4*)(p + 4);
            float v[8] = {p0.x, p0.y, p0.z, p0.w, p1.x, p1.y, p1.z, p1.w};
            short8 h, l;
            for (int j = 0; j < 8; j++) {
                u16 hb = f2bf(v[j]);
                h[j] = (short)hb;
                l[j] = (short)f2bf(v[j] - bf2f(hb));
            }
            hi[mt][k0] = h; lo[mt][k0] = l;
            *(short8*)(xb + b * 2048 + row * 64 + kof) = h;  // bf16 x for GEMM1
        }
    }
    f32x4 zero = {0.f, 0.f, 0.f, 0.f};
    f32x4 acc[2][2];
    for (int mt = 0; mt < 2; mt++) for (int nt = 0; nt < 2; nt++) acc[mt][nt] = zero;
    for (int k0 = 0; k0 < 2; k0++)
        for (int mt = 0; mt < 2; mt++)
            for (int nt = 0; nt < 2; nt++) {
                acc[mt][nt] = __builtin_amdgcn_mfma_f32_16x16x32_bf16(hi[mt][k0], hi[nt][k0], acc[mt][nt], 0, 0, 0);
                acc[mt][nt] = __builtin_amdgcn_mfma_f32_16x16x32_bf16(hi[mt][k0], lo[nt][k0], acc[mt][nt], 0, 0, 0);
                acc[mt][nt] = __builtin_amdgcn_mfma_f32_16x16x32_bf16(lo[mt][k0], hi[nt][k0], acc[mt][nt], 0, 0, 0);
            }
    float pacc = 0.f;
    for (int mt = 0; mt < 2; mt++)
        for (int nt = 0; nt < 2; nt++)
            for (int r = 0; r < 4; r++) {
                int row = mt * 16 + quad * 4 + r;
                int col = nt * 16 + r16;
                if (col > row) {
                    int p = 31 * row - (row * (row - 1)) / 2 + (col - row - 1);
                    pacc += acc[mt][nt][r] * Wc[64 + p];
                }
            }
    for (int off = 1; off < 64; off <<= 1) pacc += __shfl_xor(pacc, off);
    if (lane == 0) spair[b] = pacc;
}

// ---------------------------------------------------------------------------
// Kernel 2: fp32 -> bf16 transpose with optional per-K row scale (BN1 fold)
// ---------------------------------------------------------------------------
__global__ __launch_bounds__(256) void k_transpose_bf16(const float* __restrict__ W,
                                                        const float* __restrict__ scale,
                                                        u16* __restrict__ WT,
                                                        int K, int N) {
    __shared__ float tile[32][33];
    const int nb = blockIdx.x * 32, kb = blockIdx.y * 32;
    const int tx = threadIdx.x & 31, ty = threadIdx.x >> 5;  // ty 0..7
    if (scale) {
        for (int r = ty; r < 32; r += 8)
            tile[r][tx] = scale[kb + r] * W[(long)(kb + r) * N + nb + tx];
    } else {
        for (int r = ty; r < 32; r += 8)
            tile[r][tx] = W[(long)(kb + r) * N + nb + tx];
    }
    __syncthreads();
    for (int r = ty; r < 32; r += 8) WT[(long)(nb + r) * K + kb + tx] = f2bf(tile[tx][r]);
}

// ---------------------------------------------------------------------------
// Kernel 3: bf16 GEMM, BK=64, XOR-swizzled LDS (conflict-free ds_read_b128),
//           XCD-aware 1D block swizzle. C = relu(A@Bt^T + bias) -> bf16
//           + per-column sum/sumsq atomics. M hardcoded 16384 (128 bands).
// ---------------------------------------------------------------------------
__global__ __launch_bounds__(256) void gemm_bn(const u16* __restrict__ A,
                                               const u16* __restrict__ Bt,
                                               const float* __restrict__ bias,
                                               u16* __restrict__ C,
                                               float* __restrict__ sums,
                                               float* __restrict__ ssq,
                                               int N, int K, int lognb) {
    __shared__ u16 lA[128 * 64];
    __shared__ u16 lB[128 * 64];
    const int tid = threadIdx.x;
    const int lane = tid & 63, wave = tid >> 6;
    const int wm = wave >> 1, wn = wave & 1;
    const int quad = lane >> 4, r16 = lane & 15;
    const int px = r16 & 7;
    // XCD swizzle: lid%8 = XCD; within an XCD, consecutive blocks share an A band
    const int lid = blockIdx.x;
    const int xcd = lid & 7, t = lid >> 3;
    const int nbk = t & ((1 << lognb) - 1);
    const int mbk = (xcd << 4) + (t >> lognb);   // 16 bands per XCD (M=16384)
    const long m0 = (long)mbk * 128;
    const long n0 = (long)nbk * 128;

    f32x4 zero = {0.f, 0.f, 0.f, 0.f};
    f32x4 acc[4][4];
    for (int mt = 0; mt < 4; mt++) for (int nt = 0; nt < 4; nt++) acc[mt][nt] = zero;

    for (long k0 = 0; k0 < K; k0 += 64) {
        __syncthreads();
        for (int i = 0; i < 4; i++) {
            const int c = tid + 256 * i;            // 0..1023: 128 rows x 8 chunks
            const int row = c >> 3, pos = c & 7;
            const int g = pos ^ (row & 7);          // stored chunk at pos is global chunk g
            const u16* ga = A + (m0 + row) * K + k0 + g * 8;
            const u16* gb = Bt + (n0 + row) * K + k0 + g * 8;
            __builtin_amdgcn_global_load_lds((const __attribute__((address_space(1))) void*)ga,
                                             (__attribute__((address_space(3))) void*)(&lA[c * 8]), 16, 0, 0);
            __builtin_amdgcn_global_load_lds((const __attribute__((address_space(1))) void*)gb,
                                             (__attribute__((address_space(3))) void*)(&lB[c * 8]), 16, 0, 0);
        }
        __syncthreads();
        for (int ks = 0; ks < 2; ks++) {
            short8 af[4], bfr[4];
            const int jb = ((ks << 2) + quad) ^ px;  // swizzled chunk position
            for (int mt = 0; mt < 4; mt++)
                af[mt] = *(const short8*)&lA[(wm * 64 + mt * 16 + r16) * 64 + jb * 8];
            for (int nt = 0; nt < 4; nt++)
                bfr[nt] = *(const short8*)&lB[(wn * 64 + nt * 16 + r16) * 64 + jb * 8];
            for (int mt = 0; mt < 4; mt++)
                for (int nt = 0; nt < 4; nt++)
                    acc[mt][nt] = __builtin_amdgcn_mfma_f32_16x16x32_bf16(af[mt], bfr[nt], acc[mt][nt], 0, 0, 0);
        }
    }

    for (int nt = 0; nt < 4; nt++) {
        const int col = (int)n0 + wn * 64 + nt * 16 + r16;
        const float bcol = bias[col];
        float s = 0.f, sq = 0.f;
        for (int mt = 0; mt < 4; mt++)
            for (int r = 0; r < 4; r++) {
                const long row = m0 + wm * 64 + mt * 16 + quad * 4 + r;
                float v = acc[mt][nt][r] + bcol;
                v = fmaxf(v, 0.f);
                C[row * N + col] = f2bf(v);
                s += v; sq += v * v;
            }
        s += __shfl_xor(s, 16);  s += __shfl_xor(s, 32);
        sq += __shfl_xor(sq, 16); sq += __shfl_xor(sq, 32);
        if (quad == 0) { atomicAdd(&sums[col], s); atomicAdd(&ssq[col], sq); }
    }
}

// ---------------------------------------------------------------------------
// Kernel 4: finalize BN affine: a = g*rsqrt(var+eps), c = beta - a*mean
// ---------------------------------------------------------------------------
__global__ void k_stat(const float* __restrict__ sums, const float* __restrict__ ssq,
                       const float* __restrict__ g, const float* __restrict__ beta,
                       float* __restrict__ a, float* __restrict__ c, int n, float invB) {
    const int k = blockIdx.x * 256 + threadIdx.x;
    if (k < n) {
        const float m = sums[k] * invB;
        const float var = ssq[k] * invB - m * m;
        const float s = g[k] * rsqrtf(var + 1e-5f);
        a[k] = s; c[k] = beta[k] - s * m;
    }
}

// ---------------------------------------------------------------------------
// Kernel 5: b2a[n] = b2[n] + sum_k c1[k]*W2[k,n]  (BN1 shift folded into bias)
// ---------------------------------------------------------------------------
__global__ __launch_bounds__(64) void k_b2adj(const float* __restrict__ W2,
                                              const float* __restrict__ c1,
                                              const float* __restrict__ b2,
                                              float* __restrict__ b2a) {
    const int col = blockIdx.x, lane = threadIdx.x;
    float s = 0.f;
    for (int k = lane; k < 1024; k += 64) s += c1[k] * W2[(long)k * 512 + col];
    for (int off = 1; off < 64; off <<= 1) s += __shfl_xor(s, off);
    if (lane == 0) b2a[col] = b2[col] + s;
}

// ---------------------------------------------------------------------------
// Kernel 6: fold GEMM3 + concat + head: v[k] = W3[k,:].Wc[:64]; c0 = b3.Wc+bc
// ---------------------------------------------------------------------------
__global__ void k_v(const float* __restrict__ W3, const float* __restrict__ b3,
                    const float* __restrict__ Wc, const float* __restrict__ bc,
                    float* __restrict__ v, float* __restrict__ c0) {
    const int k = blockIdx.x * 256 + threadIdx.x;
    if (k < 512) {
        float s = 0.f;
        for (int j = 0; j < 64; j++) s += W3[k * 64 + j] * Wc[j];
        v[k] = s;
    }
    if (k == 0) {
        float s = 0.f;
        for (int j = 0; j < 64; j++) s += b3[j] * Wc[j];
        *c0 = s + bc[0];
    }
}

// ---------------------------------------------------------------------------
// Kernel 7: out[b] = sum_k (a2[k]*h2[b,k]+c2[k])*v[k] + spair[b] + c0
// ---------------------------------------------------------------------------
__global__ __launch_bounds__(256) void k_final(const u16* __restrict__ h2,
                                               const float* __restrict__ a2,
                                               const float* __restrict__ c2,
                                               const float* __restrict__ v,
                                               const float* __restrict__ c0,
                                               const float* __restrict__ spair,
                                               float* __restrict__ out) {
    const int wave = threadIdx.x >> 6, lane = threadIdx.x & 63;
    const long b = (long)blockIdx.x * 4 + wave;
    const int k0 = lane * 8;
    short8 hv = *(const short8*)&h2[b * 512 + k0];
    float acc = 0.f;
    for (int j = 0; j < 8; j++) {
        const int k = k0 + j;
        const float f = bf2f((u16)hv[j]);
        acc += (a2[k] * f + c2[k]) * v[k];
    }
    for (int off = 1; off < 64; off <<= 1) acc += __shfl_xor(acc, off);
    if (lane == 0) out[b] = acc + spair[b] + c0[0];
}

// ---------------------------------------------------------------------------
extern "C" void kernel_launch(void* const* d_in, const int* in_sizes, int n_in,
                              void* d_out, int out_size, void* d_ws, size_t ws_size,
                              hipStream_t stream) {
    const float* x     = (const float*)d_in[0];
    const float* W1    = (const float*)d_in[1];
    const float* b1    = (const float*)d_in[2];
    const float* g1    = (const float*)d_in[3];
    const float* beta1 = (const float*)d_in[4];
    const float* W2    = (const float*)d_in[5];
    const float* b2    = (const float*)d_in[6];
    const float* g2    = (const float*)d_in[7];
    const float* beta2 = (const float*)d_in[8];
    const float* W3    = (const float*)d_in[9];
    const float* b3    = (const float*)d_in[10];
    const float* Wc    = (const float*)d_in[11];
    const float* bc    = (const float*)d_in[12];
    float* out = (float*)d_out;

    char* ws = (char*)d_ws;
    size_t o = 0;
    u16* xb  = (u16*)(ws + o); o += BATCH * 2048 * 2;       // 67.1 MB
    u16* w1t = (u16*)(ws + o); o += 2048L * 1024 * 2;       //  4.2 MB
    u16* w2t = (u16*)(ws + o); o += 1024L * 512 * 2;        //  1.0 MB
    u16* h1b = (u16*)(ws + o); o += BATCH * 1024 * 2;       // 33.6 MB (raw relu1)
    u16* h2b = (u16*)(ws + o); o += BATCH * 512 * 2;        // 16.8 MB (raw relu2)
    float* spair = (float*)(ws + o); o += BATCH * 4;
    float* stats = (float*)(ws + o); o += 3072 * 4;
    float* sums1 = stats, *ssq1 = stats + 1024, *sums2 = stats + 2048, *ssq2 = stats + 2560;
    float* a1 = (float*)(ws + o); o += 1024 * 4;
    float* c1 = (float*)(ws + o); o += 1024 * 4;
    float* a2 = (float*)(ws + o); o += 512 * 4;
    float* c2 = (float*)(ws + o); o += 512 * 4;
    float* vv = (float*)(ws + o); o += 512 * 4;
    float* c0 = (float*)(ws + o); o += 4;
    float* b2a = (float*)(ws + o); o += 512 * 4;

    hipMemsetAsync(stats, 0, 3072 * 4, stream);
    k_gram<<<4096, 256, 0, stream>>>(x, Wc, xb, spair);
    k_transpose_bf16<<<dim3(1024 / 32, 2048 / 32), 256, 0, stream>>>(W1, nullptr, w1t, 2048, 1024);
    gemm_bn<<<1024, 256, 0, stream>>>(xb, w1t, b1, h1b, sums1, ssq1, 1024, 2048, 3);
    k_stat<<<4, 256, 0, stream>>>(sums1, ssq1, g1, beta1, a1, c1, 1024, 1.f / 16384.f);
    k_transpose_bf16<<<dim3(512 / 32, 1024 / 32), 256, 0, stream>>>(W2, a1, w2t, 1024, 512);
    k_b2adj<<<512, 64, 0, stream>>>(W2, c1, b2, b2a);
    gemm_bn<<<512, 256, 0, stream>>>(h1b, w2t, b2a, h2b, sums2, ssq2, 512, 1024, 2);
    k_stat<<<2, 256, 0, stream>>>(sums2, ssq2, g2, beta2, a2, c2, 512, 1.f / 16384.f);
    k_v<<<2, 256, 0, stream>>>(W3, b3, Wc, bc, vv, c0);
    k_final<<<4096, 256, 0, stream>>>(h2b, a2, c2, vv, c0, spair, out);
}

// Round 4
// 336.642 us; speedup vs baseline: 1.2176x; 1.0868x over previous
//
#include <hip/hip_runtime.h>
#include <stdint.h>

typedef unsigned short u16;
typedef unsigned char u8;
typedef __attribute__((ext_vector_type(8))) short short8;
typedef __attribute__((ext_vector_type(4))) float f32x4;

#define BATCH 16384L
#define WSCALE 64.0f
#define INV_WSCALE (1.0f / 64.0f)

__device__ __forceinline__ u16 f2bf(float f) {
    union { float f; uint32_t u; } cv; cv.f = f;
    uint32_t u = cv.u;
    u = (u + 0x7fffu + ((u >> 16) & 1u)) >> 16;
    return (u16)u;
}
__device__ __forceinline__ float bf2f(u16 h) {
    union { uint32_t u; float f; } cv; cv.u = ((uint32_t)h) << 16;
    return cv.f;
}
// pack 2 floats -> 2 fp8 e4m3 (OCP); HI selects the halfword (must be imm)
template<bool HI>
__device__ __forceinline__ uint32_t fp8pk(float a, float b, uint32_t old) {
    return (uint32_t)__builtin_amdgcn_cvt_pk_fp8_f32(a, b, (int)old, HI);
}
__device__ __forceinline__ u8 f2fp8(float v) {
    return (u8)(__builtin_amdgcn_cvt_pk_fp8_f32(v, v, 0, false) & 0xff);
}

// ---------------------------------------------------------------------------
// Kernel 1: per-batch gram pairs (hi/lo split bf16 MFMA ~ fp32 accuracy)
//           + emit fp8 copy of x for GEMM1 (reads x exactly once)
// ---------------------------------------------------------------------------
__global__ __launch_bounds__(256) void k_gram(const float* __restrict__ x,
                                              const float* __restrict__ Wc,
                                              u8* __restrict__ xb,
                                              float* __restrict__ spair) {
    const int wave = threadIdx.x >> 6;
    const int lane = threadIdx.x & 63;
    const long b = (long)blockIdx.x * 4 + wave;
    const int r16 = lane & 15, quad = lane >> 4;
    const float* xg = x + b * 2048;

    short8 hi[2][2], lo[2][2];
    for (int mt = 0; mt < 2; mt++) {
        for (int k0 = 0; k0 < 2; k0++) {
            const int row = mt * 16 + r16;
            const int kof = k0 * 32 + quad * 8;
            const float* p = xg + row * 64 + kof;
            float4 p0 = *(const float4*)p;
            float4 p1 = *(const float4*)(p + 4);
            float v[8] = {p0.x, p0.y, p0.z, p0.w, p1.x, p1.y, p1.z, p1.w};
            short8 h, l;
            for (int j = 0; j < 8; j++) {
                u16 hb = f2bf(v[j]);
                h[j] = (short)hb;
                l[j] = (short)f2bf(v[j] - bf2f(hb));
            }
            hi[mt][k0] = h; lo[mt][k0] = l;
            uint32_t w0 = fp8pk<false>(v[0], v[1], 0); w0 = fp8pk<true>(v[2], v[3], w0);
            uint32_t w1 = fp8pk<false>(v[4], v[5], 0); w1 = fp8pk<true>(v[6], v[7], w1);
            *(uint2*)(xb + b * 2048 + row * 64 + kof) = make_uint2(w0, w1);
        }
    }
    f32x4 zero = {0.f, 0.f, 0.f, 0.f};
    f32x4 acc[2][2];
    for (int mt = 0; mt < 2; mt++) for (int nt = 0; nt < 2; nt++) acc[mt][nt] = zero;
    for (int k0 = 0; k0 < 2; k0++)
        for (int mt = 0; mt < 2; mt++)
            for (int nt = 0; nt < 2; nt++) {
                acc[mt][nt] = __builtin_amdgcn_mfma_f32_16x16x32_bf16(hi[mt][k0], hi[nt][k0], acc[mt][nt], 0, 0, 0);
                acc[mt][nt] = __builtin_amdgcn_mfma_f32_16x16x32_bf16(hi[mt][k0], lo[nt][k0], acc[mt][nt], 0, 0, 0);
                acc[mt][nt] = __builtin_amdgcn_mfma_f32_16x16x32_bf16(lo[mt][k0], hi[nt][k0], acc[mt][nt], 0, 0, 0);
            }
    float pacc = 0.f;
    for (int mt = 0; mt < 2; mt++)
        for (int nt = 0; nt < 2; nt++)
            for (int r = 0; r < 4; r++) {
                int row = mt * 16 + quad * 4 + r;
                int col = nt * 16 + r16;
                if (col > row) {
                    int p = 31 * row - (row * (row - 1)) / 2 + (col - row - 1);
                    pacc += acc[mt][nt][r] * Wc[64 + p];
                }
            }
    for (int off = 1; off < 64; off <<= 1) pacc += __shfl_xor(pacc, off);
    if (lane == 0) spair[b] = pacc;
}

// ---------------------------------------------------------------------------
// Kernel 2: fp32 -> fp8 transpose, value = WSCALE * (scale[k]?) * W[k,n]
// ---------------------------------------------------------------------------
__global__ __launch_bounds__(256) void k_transpose_fp8(const float* __restrict__ W,
                                                       const float* __restrict__ scale,
                                                       u8* __restrict__ WT,
                                                       int K, int N) {
    __shared__ float tile[32][33];
    const int nb = blockIdx.x * 32, kb = blockIdx.y * 32;
    const int tx = threadIdx.x & 31, ty = threadIdx.x >> 5;  // ty 0..7
    if (scale) {
        for (int r = ty; r < 32; r += 8)
            tile[r][tx] = scale[kb + r] * W[(long)(kb + r) * N + nb + tx];
    } else {
        for (int r = ty; r < 32; r += 8)
            tile[r][tx] = W[(long)(kb + r) * N + nb + tx];
    }
    __syncthreads();
    for (int r = ty; r < 32; r += 8)
        WT[(long)(nb + r) * K + kb + tx] = f2fp8(WSCALE * tile[tx][r]);
}

// ---------------------------------------------------------------------------
// Kernel 3: fp8 e4m3 GEMM, BK=128 (32 KB LDS), XOR-swizzled chunks,
//           XCD-aware 1D swizzle. C = relu(inv*acc + bias) -> fp8
//           + per-column sum/sumsq atomics. M=16384 (128 bands).
// ---------------------------------------------------------------------------
template<int LOGNB>
__global__ __launch_bounds__(256) void gemm_bn(const u8* __restrict__ A,
                                               const u8* __restrict__ Bt,
                                               const float* __restrict__ bias,
                                               u8* __restrict__ C,
                                               float* __restrict__ sums,
                                               float* __restrict__ ssq,
                                               int N, int K, float inv) {
    __shared__ u8 lA[128 * 128];
    __shared__ u8 lB[128 * 128];
    const int tid = threadIdx.x;
    const int lane = tid & 63, wave = tid >> 6;
    const int wm = wave >> 1, wn = wave & 1;
    const int quad = lane >> 4, r16 = lane & 15;
    const int lid = blockIdx.x;
    const int xcd = lid & 7, t = lid >> 3;
    const int nbk = t & ((1 << LOGNB) - 1);
    const int mbk = (xcd << 4) + (t >> LOGNB);   // 16 bands per XCD
    const long m0 = (long)mbk * 128;
    const long n0 = (long)nbk * 128;

    f32x4 zero = {0.f, 0.f, 0.f, 0.f};
    f32x4 acc[4][4];
    for (int mt = 0; mt < 4; mt++) for (int nt = 0; nt < 4; nt++) acc[mt][nt] = zero;

    const int gcb = quad >> 1, off8 = (quad & 1) * 8;   // chunk-sub-index pieces

    for (long k0 = 0; k0 < K; k0 += 128) {
        __syncthreads();
        for (int i = 0; i < 4; i++) {
            const int c = tid + 256 * i;            // 0..1023: 128 rows x 8 chunks
            const int row = c >> 3, pos = c & 7;
            const int g = pos ^ (row & 7);          // source global chunk
            const u8* ga = A + (m0 + row) * K + k0 + g * 16;
            const u8* gb = Bt + (n0 + row) * K + k0 + g * 16;
            __builtin_amdgcn_global_load_lds((const __attribute__((address_space(1))) void*)ga,
                                             (__attribute__((address_space(3))) void*)(&lA[c * 16]), 16, 0, 0);
            __builtin_amdgcn_global_load_lds((const __attribute__((address_space(1))) void*)gb,
                                             (__attribute__((address_space(3))) void*)(&lB[c * 16]), 16, 0, 0);
        }
        __syncthreads();
        for (int ks = 0; ks < 4; ks++) {
            const int gc = ks * 2 + gcb;            // global 16B chunk of this K-octet
            long af[4], bfr[4];
            for (int mt = 0; mt < 4; mt++) {
                const int R = wm * 64 + mt * 16 + r16;
                af[mt] = *(const long*)&lA[R * 128 + ((gc ^ (R & 7)) * 16) + off8];
            }
            for (int nt = 0; nt < 4; nt++) {
                const int R = wn * 64 + nt * 16 + r16;
                bfr[nt] = *(const long*)&lB[R * 128 + ((gc ^ (R & 7)) * 16) + off8];
            }
            for (int mt = 0; mt < 4; mt++)
                for (int nt = 0; nt < 4; nt++)
                    acc[mt][nt] = __builtin_amdgcn_mfma_f32_16x16x32_fp8_fp8(af[mt], bfr[nt], acc[mt][nt], 0, 0, 0);
        }
    }

    for (int nt = 0; nt < 4; nt++) {
        const int col = (int)n0 + wn * 64 + nt * 16 + r16;
        const float bcol = bias[col];
        float s = 0.f, sq = 0.f;
        for (int mt = 0; mt < 4; mt++)
            for (int r = 0; r < 4; r++) {
                const long row = m0 + wm * 64 + mt * 16 + quad * 4 + r;
                float v = acc[mt][nt][r] * inv + bcol;
                v = fmaxf(v, 0.f);
                C[row * N + col] = f2fp8(v);
                s += v; sq += v * v;
            }
        s += __shfl_xor(s, 16);  s += __shfl_xor(s, 32);
        sq += __shfl_xor(sq, 16); sq += __shfl_xor(sq, 32);
        if (quad == 0) { atomicAdd(&sums[col], s); atomicAdd(&ssq[col], sq); }
    }
}

// ---------------------------------------------------------------------------
// Kernel 4: finalize BN affine: a = g*rsqrt(var+eps), c = beta - a*mean
// ---------------------------------------------------------------------------
__global__ void k_stat(const float* __restrict__ sums, const float* __restrict__ ssq,
                       const float* __restrict__ g, const float* __restrict__ beta,
                       float* __restrict__ a, float* __restrict__ c, int n, float invB) {
    const int k = blockIdx.x * 256 + threadIdx.x;
    if (k < n) {
        const float m = sums[k] * invB;
        const float var = ssq[k] * invB - m * m;
        const float s = g[k] * rsqrtf(var + 1e-5f);
        a[k] = s; c[k] = beta[k] - s * m;
    }
}

// ---------------------------------------------------------------------------
// Kernel 5: b2a[n] = b2[n] + sum_k c1[k]*W2[k,n]  (BN1 shift folded into bias)
// ---------------------------------------------------------------------------
__global__ __launch_bounds__(64) void k_b2adj(const float* __restrict__ W2,
                                              const float* __restrict__ c1,
                                              const float* __restrict__ b2,
                                              float* __restrict__ b2a) {
    const int col = blockIdx.x, lane = threadIdx.x;
    float s = 0.f;
    for (int k = lane; k < 1024; k += 64) s += c1[k] * W2[(long)k * 512 + col];
    for (int off = 1; off < 64; off <<= 1) s += __shfl_xor(s, off);
    if (lane == 0) b2a[col] = b2[col] + s;
}

// ---------------------------------------------------------------------------
// Kernel 6: fold GEMM3 + concat + head: v[k] = W3[k,:].Wc[:64]; c0 = b3.Wc+bc
// ---------------------------------------------------------------------------
__global__ void k_v(const float* __restrict__ W3, const float* __restrict__ b3,
                    const float* __restrict__ Wc, const float* __restrict__ bc,
                    float* __restrict__ v, float* __restrict__ c0) {
    const int k = blockIdx.x * 256 + threadIdx.x;
    if (k < 512) {
        float s = 0.f;
        for (int j = 0; j < 64; j++) s += W3[k * 64 + j] * Wc[j];
        v[k] = s;
    }
    if (k == 0) {
        float s = 0.f;
        for (int j = 0; j < 64; j++) s += b3[j] * Wc[j];
        *c0 = s + bc[0];
    }
}

// ---------------------------------------------------------------------------
// Kernel 7: out[b] = sum_k (a2[k]*h2[b,k]+c2[k])*v[k] + spair[b] + c0
// ---------------------------------------------------------------------------
__global__ __launch_bounds__(256) void k_final(const u8* __restrict__ h2,
                                               const float* __restrict__ a2,
                                               const float* __restrict__ c2,
                                               const float* __restrict__ v,
                                               const float* __restrict__ c0,
                                               const float* __restrict__ spair,
                                               float* __restrict__ out) {
    const int wave = threadIdx.x >> 6, lane = threadIdx.x & 63;
    const long b = (long)blockIdx.x * 4 + wave;
    const int k0 = lane * 8;
    uint2 hv = *(const uint2*)&h2[b * 512 + k0];
    float f[8];
    f[0] = __builtin_amdgcn_cvt_f32_fp8(hv.x, 0);
    f[1] = __builtin_amdgcn_cvt_f32_fp8(hv.x, 1);
    f[2] = __builtin_amdgcn_cvt_f32_fp8(hv.x, 2);
    f[3] = __builtin_amdgcn_cvt_f32_fp8(hv.x, 3);
    f[4] = __builtin_amdgcn_cvt_f32_fp8(hv.y, 0);
    f[5] = __builtin_amdgcn_cvt_f32_fp8(hv.y, 1);
    f[6] = __builtin_amdgcn_cvt_f32_fp8(hv.y, 2);
    f[7] = __builtin_amdgcn_cvt_f32_fp8(hv.y, 3);
    float acc = 0.f;
    for (int j = 0; j < 8; j++) {
        const int k = k0 + j;
        acc += (a2[k] * f[j] + c2[k]) * v[k];
    }
    for (int off = 1; off < 64; off <<= 1) acc += __shfl_xor(acc, off);
    if (lane == 0) out[b] = acc + spair[b] + c0[0];
}

// ---------------------------------------------------------------------------
extern "C" void kernel_launch(void* const* d_in, const int* in_sizes, int n_in,
                              void* d_out, int out_size, void* d_ws, size_t ws_size,
                              hipStream_t stream) {
    const float* x     = (const float*)d_in[0];
    const float* W1    = (const float*)d_in[1];
    const float* b1    = (const float*)d_in[2];
    const float* g1    = (const float*)d_in[3];
    const float* beta1 = (const float*)d_in[4];
    const float* W2    = (const float*)d_in[5];
    const float* b2    = (const float*)d_in[6];
    const float* g2    = (const float*)d_in[7];
    const float* beta2 = (const float*)d_in[8];
    const float* W3    = (const float*)d_in[9];
    const float* b3    = (const float*)d_in[10];
    const float* Wc    = (const float*)d_in[11];
    const float* bc    = (const float*)d_in[12];
    float* out = (float*)d_out;

    char* ws = (char*)d_ws;
    size_t o = 0;
    u8* xb  = (u8*)(ws + o); o += BATCH * 2048;             // 33.6 MB fp8
    u8* w1f = (u8*)(ws + o); o += 2048L * 1024;             //  2.1 MB
    u8* w2f = (u8*)(ws + o); o += 1024L * 512;              //  0.5 MB
    u8* h1b = (u8*)(ws + o); o += BATCH * 1024;             // 16.8 MB (raw relu1, fp8)
    u8* h2b = (u8*)(ws + o); o += BATCH * 512;              //  8.4 MB (raw relu2, fp8)
    float* spair = (float*)(ws + o); o += BATCH * 4;
    float* stats = (float*)(ws + o); o += 3072 * 4;
    float* sums1 = stats, *ssq1 = stats + 1024, *sums2 = stats + 2048, *ssq2 = stats + 2560;
    float* a1 = (float*)(ws + o); o += 1024 * 4;
    float* c1 = (float*)(ws + o); o += 1024 * 4;
    float* a2 = (float*)(ws + o); o += 512 * 4;
    float* c2 = (float*)(ws + o); o += 512 * 4;
    float* vv = (float*)(ws + o); o += 512 * 4;
    float* c0 = (float*)(ws + o); o += 4;
    float* b2a = (float*)(ws + o); o += 512 * 4;

    (void)hipMemsetAsync(stats, 0, 3072 * 4, stream);
    k_gram<<<4096, 256, 0, stream>>>(x, Wc, xb, spair);
    k_transpose_fp8<<<dim3(1024 / 32, 2048 / 32), 256, 0, stream>>>(W1, nullptr, w1f, 2048, 1024);
    gemm_bn<3><<<1024, 256, 0, stream>>>(xb, w1f, b1, h1b, sums1, ssq1, 1024, 2048, INV_WSCALE);
    k_stat<<<4, 256, 0, stream>>>(sums1, ssq1, g1, beta1, a1, c1, 1024, 1.f / 16384.f);
    k_transpose_fp8<<<dim3(512 / 32, 1024 / 32), 256, 0, stream>>>(W2, a1, w2f, 1024, 512);
    k_b2adj<<<512, 64, 0, stream>>>(W2, c1, b2, b2a);
    gemm_bn<2><<<512, 256, 0, stream>>>(h1b, w2f, b2a, h2b, sums2, ssq2, 512, 1024, INV_WSCALE);
    k_stat<<<2, 256, 0, stream>>>(sums2, ssq2, g2, beta2, a2, c2, 512, 1.f / 16384.f);
    k_v<<<2, 256, 0, stream>>>(W3, b3, Wc, bc, vv, c0);
    k_final<<<4096, 256, 0, stream>>>(h2b, a2, c2, vv, c0, spair, out);
}

// Round 5
// 318.079 us; speedup vs baseline: 1.2887x; 1.0584x over previous
//
#include <hip/hip_runtime.h>
#include <stdint.h>

typedef unsigned short u16;
typedef unsigned char u8;
typedef __attribute__((ext_vector_type(8))) short short8;
typedef __attribute__((ext_vector_type(4))) float f32x4;
typedef __attribute__((ext_vector_type(16))) float f32x16;
typedef __attribute__((ext_vector_type(4))) int i32x4;
typedef __attribute__((ext_vector_type(8))) int i32x8;

#define BATCH 16384L
#define WSCALE 64.0f
#define INV_WSCALE (1.0f / 64.0f)
#define SCALE_ONE 0x7f7f7f7f   // e8m0 biased exp 127 = 1.0 in all 4 bytes

__device__ __forceinline__ u16 f2bf(float f) {
    union { float f; uint32_t u; } cv; cv.f = f;
    uint32_t u = cv.u;
    u = (u + 0x7fffu + ((u >> 16) & 1u)) >> 16;
    return (u16)u;
}
__device__ __forceinline__ float bf2f(u16 h) {
    union { uint32_t u; float f; } cv; cv.u = ((uint32_t)h) << 16;
    return cv.f;
}
template<bool HI>
__device__ __forceinline__ uint32_t fp8pk(float a, float b, uint32_t old) {
    return (uint32_t)__builtin_amdgcn_cvt_pk_fp8_f32(a, b, (int)old, HI);
}
__device__ __forceinline__ u8 f2fp8(float v) {
    return (u8)(__builtin_amdgcn_cvt_pk_fp8_f32(v, v, 0, false) & 0xff);
}

// ---------------------------------------------------------------------------
// Kernel 1: per-batch gram pairs (hi/lo split bf16 MFMA ~ fp32 accuracy)
//           + emit fp8 copy of x for GEMM1 (reads x exactly once)
// ---------------------------------------------------------------------------
__global__ __launch_bounds__(256) void k_gram(const float* __restrict__ x,
                                              const float* __restrict__ Wc,
                                              u8* __restrict__ xb,
                                              float* __restrict__ spair) {
    const int wave = threadIdx.x >> 6;
    const int lane = threadIdx.x & 63;
    const long b = (long)blockIdx.x * 4 + wave;
    const int r16 = lane & 15, quad = lane >> 4;
    const float* xg = x + b * 2048;

    short8 hi[2][2], lo[2][2];
    for (int mt = 0; mt < 2; mt++) {
        for (int k0 = 0; k0 < 2; k0++) {
            const int row = mt * 16 + r16;
            const int kof = k0 * 32 + quad * 8;
            const float* p = xg + row * 64 + kof;
            float4 p0 = *(const float4*)p;
            float4 p1 = *(const float4*)(p + 4);
            float v[8] = {p0.x, p0.y, p0.z, p0.w, p1.x, p1.y, p1.z, p1.w};
            short8 h, l;
            for (int j = 0; j < 8; j++) {
                u16 hb = f2bf(v[j]);
                h[j] = (short)hb;
                l[j] = (short)f2bf(v[j] - bf2f(hb));
            }
            hi[mt][k0] = h; lo[mt][k0] = l;
            uint32_t w0 = fp8pk<false>(v[0], v[1], 0); w0 = fp8pk<true>(v[2], v[3], w0);
            uint32_t w1 = fp8pk<false>(v[4], v[5], 0); w1 = fp8pk<true>(v[6], v[7], w1);
            *(uint2*)(xb + b * 2048 + row * 64 + kof) = make_uint2(w0, w1);
        }
    }
    f32x4 zero = {0.f, 0.f, 0.f, 0.f};
    f32x4 acc[2][2];
    for (int mt = 0; mt < 2; mt++) for (int nt = 0; nt < 2; nt++) acc[mt][nt] = zero;
    for (int k0 = 0; k0 < 2; k0++)
        for (int mt = 0; mt < 2; mt++)
            for (int nt = 0; nt < 2; nt++) {
                acc[mt][nt] = __builtin_amdgcn_mfma_f32_16x16x32_bf16(hi[mt][k0], hi[nt][k0], acc[mt][nt], 0, 0, 0);
                acc[mt][nt] = __builtin_amdgcn_mfma_f32_16x16x32_bf16(hi[mt][k0], lo[nt][k0], acc[mt][nt], 0, 0, 0);
                acc[mt][nt] = __builtin_amdgcn_mfma_f32_16x16x32_bf16(lo[mt][k0], hi[nt][k0], acc[mt][nt], 0, 0, 0);
            }
    float pacc = 0.f;
    for (int mt = 0; mt < 2; mt++)
        for (int nt = 0; nt < 2; nt++)
            for (int r = 0; r < 4; r++) {
                int row = mt * 16 + quad * 4 + r;
                int col = nt * 16 + r16;
                if (col > row) {
                    int p = 31 * row - (row * (row - 1)) / 2 + (col - row - 1);
                    pacc += acc[mt][nt][r] * Wc[64 + p];
                }
            }
    for (int off = 1; off < 64; off <<= 1) pacc += __shfl_xor(pacc, off);
    if (lane == 0) spair[b] = pacc;
}

// ---------------------------------------------------------------------------
// Kernel 2: fp32 -> fp8 transpose, value = WSCALE * (scale[k]?) * W[k,n]
// ---------------------------------------------------------------------------
__global__ __launch_bounds__(256) void k_transpose_fp8(const float* __restrict__ W,
                                                       const float* __restrict__ scale,
                                                       u8* __restrict__ WT,
                                                       int K, int N) {
    __shared__ float tile[32][33];
    const int nb = blockIdx.x * 32, kb = blockIdx.y * 32;
    const int tx = threadIdx.x & 31, ty = threadIdx.x >> 5;  // ty 0..7
    if (scale) {
        for (int r = ty; r < 32; r += 8)
            tile[r][tx] = scale[kb + r] * W[(long)(kb + r) * N + nb + tx];
    } else {
        for (int r = ty; r < 32; r += 8)
            tile[r][tx] = W[(long)(kb + r) * N + nb + tx];
    }
    __syncthreads();
    for (int r = ty; r < 32; r += 8)
        WT[(long)(nb + r) * K + kb + tx] = f2fp8(WSCALE * tile[tx][r]);
}

// ---------------------------------------------------------------------------
// 32B fragment from XOR-swizzled LDS row: two independently-indexed 16B chunks
// (keeps global-K order exact regardless of row parity)
// ---------------------------------------------------------------------------
__device__ __forceinline__ i32x8 frag32(const u8* __restrict__ lds, int R, int cb) {
    const int s = R & 7;
    i32x4 lo = *(const i32x4*)&lds[R * 128 + ((cb ^ s) * 16)];
    i32x4 hi = *(const i32x4*)&lds[R * 128 + (((cb + 1) ^ s) * 16)];
    i32x8 r;
    r[0] = lo[0]; r[1] = lo[1]; r[2] = lo[2]; r[3] = lo[3];
    r[4] = hi[0]; r[5] = hi[1]; r[6] = hi[2]; r[7] = hi[3];
    return r;
}

// ---------------------------------------------------------------------------
// Kernel 3: MX-scaled fp8 GEMM (mfma_scale 32x32x64, scales = 1.0), BK=128,
//           XOR-swizzled LDS, XCD-aware swizzle. C = relu(inv*acc+bias) -> fp8
//           + per-column sum/sumsq atomics. M=16384 (128 bands).
// ---------------------------------------------------------------------------
template<int LOGNB>
__global__ __launch_bounds__(256) void gemm_bn(const u8* __restrict__ A,
                                               const u8* __restrict__ Bt,
                                               const float* __restrict__ bias,
                                               u8* __restrict__ C,
                                               float* __restrict__ sums,
                                               float* __restrict__ ssq,
                                               int N, int K, float inv) {
    __shared__ u8 lA[128 * 128];
    __shared__ u8 lB[128 * 128];
    const int tid = threadIdx.x;
    const int lane = tid & 63, wave = tid >> 6;
    const int wm = wave >> 1, wn = wave & 1;
    const int r32 = lane & 31, hf = lane >> 5;
    const int lid = blockIdx.x;
    const int xcd = lid & 7, t = lid >> 3;
    const int nbk = t & ((1 << LOGNB) - 1);
    const int mbk = (xcd << 4) + (t >> LOGNB);   // 16 bands per XCD
    const long m0 = (long)mbk * 128;
    const long n0 = (long)nbk * 128;

    f32x16 acc[2][2];
    for (int mt = 0; mt < 2; mt++)
        for (int nt = 0; nt < 2; nt++)
            for (int r = 0; r < 16; r++) acc[mt][nt][r] = 0.f;

    for (long k0 = 0; k0 < K; k0 += 128) {
        __syncthreads();
        for (int i = 0; i < 4; i++) {
            const int c = tid + 256 * i;            // 0..1023: 128 rows x 8 chunks
            const int row = c >> 3, pos = c & 7;
            const int g = pos ^ (row & 7);          // source global chunk
            const u8* ga = A + (m0 + row) * K + k0 + g * 16;
            const u8* gb = Bt + (n0 + row) * K + k0 + g * 16;
            __builtin_amdgcn_global_load_lds((const __attribute__((address_space(1))) void*)ga,
                                             (__attribute__((address_space(3))) void*)(&lA[c * 16]), 16, 0, 0);
            __builtin_amdgcn_global_load_lds((const __attribute__((address_space(1))) void*)gb,
                                             (__attribute__((address_space(3))) void*)(&lB[c * 16]), 16, 0, 0);
        }
        __syncthreads();
        for (int km = 0; km < 2; km++) {
            const int cb = km * 4 + hf * 2;         // first 16B chunk of this lane's 32B
            i32x8 af[2], bfr[2];
            for (int mt = 0; mt < 2; mt++)
                af[mt] = frag32(lA, wm * 64 + mt * 32 + r32, cb);
            for (int nt = 0; nt < 2; nt++)
                bfr[nt] = frag32(lB, wn * 64 + nt * 32 + r32, cb);
            for (int mt = 0; mt < 2; mt++)
                for (int nt = 0; nt < 2; nt++)
                    acc[mt][nt] = __builtin_amdgcn_mfma_scale_f32_32x32x64_f8f6f4(
                        af[mt], bfr[nt], acc[mt][nt], 0, 0,
                        0, SCALE_ONE, 0, SCALE_ONE);
        }
    }

    // epilogue: C/D 32x32 layout: col=lane&31, row=(reg&3)+8*(reg>>2)+4*(lane>>5)
    for (int nt = 0; nt < 2; nt++) {
        const int col = (int)n0 + wn * 64 + nt * 32 + r32;
        const float bcol = bias[col];
        float s = 0.f, sq = 0.f;
        for (int mt = 0; mt < 2; mt++)
            for (int r = 0; r < 16; r++) {
                const long row = m0 + wm * 64 + mt * 32 + 4 * hf + (r & 3) + 8 * (r >> 2);
                float v = acc[mt][nt][r] * inv + bcol;
                v = fmaxf(v, 0.f);
                C[row * N + col] = f2fp8(v);
                s += v; sq += v * v;
            }
        s += __shfl_xor(s, 32);
        sq += __shfl_xor(sq, 32);
        if (hf == 0) { atomicAdd(&sums[col], s); atomicAdd(&ssq[col], sq); }
    }
}

// ---------------------------------------------------------------------------
// Kernel 4: finalize BN affine: a = g*rsqrt(var+eps), c = beta - a*mean
// ---------------------------------------------------------------------------
__global__ void k_stat(const float* __restrict__ sums, const float* __restrict__ ssq,
                       const float* __restrict__ g, const float* __restrict__ beta,
                       float* __restrict__ a, float* __restrict__ c, int n, float invB) {
    const int k = blockIdx.x * 256 + threadIdx.x;
    if (k < n) {
        const float m = sums[k] * invB;
        const float var = ssq[k] * invB - m * m;
        const float s = g[k] * rsqrtf(var + 1e-5f);
        a[k] = s; c[k] = beta[k] - s * m;
    }
}

// ---------------------------------------------------------------------------
// Kernel 4b: stat2 + head-fold in one dispatch.
//  blocks 0,1: BN2 affine.  block 2: v[k]=W3[k,:].Wc[:64] (k=tid,tid+256), c0.
// ---------------------------------------------------------------------------
__global__ void k_stat2v(const float* __restrict__ sums, const float* __restrict__ ssq,
                         const float* __restrict__ g, const float* __restrict__ beta,
                         float* __restrict__ a, float* __restrict__ c, float invB,
                         const float* __restrict__ W3, const float* __restrict__ b3,
                         const float* __restrict__ Wc, const float* __restrict__ bc,
                         float* __restrict__ v, float* __restrict__ c0) {
    if (blockIdx.x < 2) {
        const int k = blockIdx.x * 256 + threadIdx.x;
        const float m = sums[k] * invB;
        const float var = ssq[k] * invB - m * m;
        const float s = g[k] * rsqrtf(var + 1e-5f);
        a[k] = s; c[k] = beta[k] - s * m;
    } else {
        for (int k = threadIdx.x; k < 512; k += 256) {
            float s = 0.f;
            for (int j = 0; j < 64; j++) s += W3[k * 64 + j] * Wc[j];
            v[k] = s;
        }
        if (threadIdx.x == 0) {
            float s = 0.f;
            for (int j = 0; j < 64; j++) s += b3[j] * Wc[j];
            *c0 = s + bc[0];
        }
    }
}

// ---------------------------------------------------------------------------
// Kernel 5: b2a[n] = b2[n] + sum_k c1[k]*W2[k,n]  (BN1 shift folded into bias)
// ---------------------------------------------------------------------------
__global__ __launch_bounds__(64) void k_b2adj(const float* __restrict__ W2,
                                              const float* __restrict__ c1,
                                              const float* __restrict__ b2,
                                              float* __restrict__ b2a) {
    const int col = blockIdx.x, lane = threadIdx.x;
    float s = 0.f;
    for (int k = lane; k < 1024; k += 64) s += c1[k] * W2[(long)k * 512 + col];
    for (int off = 1; off < 64; off <<= 1) s += __shfl_xor(s, off);
    if (lane == 0) b2a[col] = b2[col] + s;
}

// ---------------------------------------------------------------------------
// Kernel 7: out[b] = sum_k (a2[k]*h2[b,k]+c2[k])*v[k] + spair[b] + c0
// ---------------------------------------------------------------------------
__global__ __launch_bounds__(256) void k_final(const u8* __restrict__ h2,
                                               const float* __restrict__ a2,
                                               const float* __restrict__ c2,
                                               const float* __restrict__ v,
                                               const float* __restrict__ c0,
                                               const float* __restrict__ spair,
                                               float* __restrict__ out) {
    const int wave = threadIdx.x >> 6, lane = threadIdx.x & 63;
    const long b = (long)blockIdx.x * 4 + wave;
    const int k0 = lane * 8;
    uint2 hv = *(const uint2*)&h2[b * 512 + k0];
    float f[8];
    f[0] = __builtin_amdgcn_cvt_f32_fp8(hv.x, 0);
    f[1] = __builtin_amdgcn_cvt_f32_fp8(hv.x, 1);
    f[2] = __builtin_amdgcn_cvt_f32_fp8(hv.x, 2);
    f[3] = __builtin_amdgcn_cvt_f32_fp8(hv.x, 3);
    f[4] = __builtin_amdgcn_cvt_f32_fp8(hv.y, 0);
    f[5] = __builtin_amdgcn_cvt_f32_fp8(hv.y, 1);
    f[6] = __builtin_amdgcn_cvt_f32_fp8(hv.y, 2);
    f[7] = __builtin_amdgcn_cvt_f32_fp8(hv.y, 3);
    float acc = 0.f;
    for (int j = 0; j < 8; j++) {
        const int k = k0 + j;
        acc += (a2[k] * f[j] + c2[k]) * v[k];
    }
    for (int off = 1; off < 64; off <<= 1) acc += __shfl_xor(acc, off);
    if (lane == 0) out[b] = acc + spair[b] + c0[0];
}

// ---------------------------------------------------------------------------
extern "C" void kernel_launch(void* const* d_in, const int* in_sizes, int n_in,
                              void* d_out, int out_size, void* d_ws, size_t ws_size,
                              hipStream_t stream) {
    const float* x     = (const float*)d_in[0];
    const float* W1    = (const float*)d_in[1];
    const float* b1    = (const float*)d_in[2];
    const float* g1    = (const float*)d_in[3];
    const float* beta1 = (const float*)d_in[4];
    const float* W2    = (const float*)d_in[5];
    const float* b2    = (const float*)d_in[6];
    const float* g2    = (const float*)d_in[7];
    const float* beta2 = (const float*)d_in[8];
    const float* W3    = (const float*)d_in[9];
    const float* b3    = (const float*)d_in[10];
    const float* Wc    = (const float*)d_in[11];
    const float* bc    = (const float*)d_in[12];
    float* out = (float*)d_out;

    char* ws = (char*)d_ws;
    size_t o = 0;
    u8* xb  = (u8*)(ws + o); o += BATCH * 2048;             // 33.6 MB fp8
    u8* w1f = (u8*)(ws + o); o += 2048L * 1024;             //  2.1 MB
    u8* w2f = (u8*)(ws + o); o += 1024L * 512;              //  0.5 MB
    u8* h1b = (u8*)(ws + o); o += BATCH * 1024;             // 16.8 MB (raw relu1, fp8)
    u8* h2b = (u8*)(ws + o); o += BATCH * 512;              //  8.4 MB (raw relu2, fp8)
    float* spair = (float*)(ws + o); o += BATCH * 4;
    float* stats = (float*)(ws + o); o += 3072 * 4;
    float* sums1 = stats, *ssq1 = stats + 1024, *sums2 = stats + 2048, *ssq2 = stats + 2560;
    float* a1 = (float*)(ws + o); o += 1024 * 4;
    float* c1 = (float*)(ws + o); o += 1024 * 4;
    float* a2 = (float*)(ws + o); o += 512 * 4;
    float* c2 = (float*)(ws + o); o += 512 * 4;
    float* vv = (float*)(ws + o); o += 512 * 4;
    float* c0 = (float*)(ws + o); o += 4;
    float* b2a = (float*)(ws + o); o += 512 * 4;

    (void)hipMemsetAsync(stats, 0, 3072 * 4, stream);
    k_gram<<<4096, 256, 0, stream>>>(x, Wc, xb, spair);
    k_transpose_fp8<<<dim3(1024 / 32, 2048 / 32), 256, 0, stream>>>(W1, nullptr, w1f, 2048, 1024);
    gemm_bn<3><<<1024, 256, 0, stream>>>(xb, w1f, b1, h1b, sums1, ssq1, 1024, 2048, INV_WSCALE);
    k_stat<<<4, 256, 0, stream>>>(sums1, ssq1, g1, beta1, a1, c1, 1024, 1.f / 16384.f);
    k_transpose_fp8<<<dim3(512 / 32, 1024 / 32), 256, 0, stream>>>(W2, a1, w2f, 1024, 512);
    k_b2adj<<<512, 64, 0, stream>>>(W2, c1, b2, b2a);
    gemm_bn<2><<<512, 256, 0, stream>>>(h1b, w2f, b2a, h2b, sums2, ssq2, 512, 1024, INV_WSCALE);
    k_stat2v<<<3, 256, 0, stream>>>(sums2, ssq2, g2, beta2, a2, c2, 1.f / 16384.f,
                                    W3, b3, Wc, bc, vv, c0);
    k_final<<<4096, 256, 0, stream>>>(h2b, a2, c2, vv, c0, spair, out);
}